// Round 1
// baseline (1904.832 us; speedup 1.0000x reference)
//
#include <hip/hip_runtime.h>
#include <hip/hip_bf16.h>

// Axial rel-pos attention, MI355X gfx950.
// Shapes: W=192 seq, B=384 batch (=2*192), C=128, 8 heads, hd=16.

typedef unsigned short u16;
typedef short bf16x8 __attribute__((ext_vector_type(8)));
typedef float f32x4 __attribute__((ext_vector_type(4)));

__device__ inline u16 f2bf(float f) {
    union { float f; unsigned u; } a; a.f = f;
    unsigned u = a.u;
    unsigned r = u + 0x7FFFu + ((u >> 16) & 1u);   // RNE
    return (u16)(r >> 16);
}

// ---------------- LayerNorm + transpose (feat[w,s*192+h] -> x2[h,s*192+w]) ----
__global__ __launch_bounds__(256) void ln_kernel(const float* __restrict__ feat,
                                                 const float* __restrict__ g,
                                                 const float* __restrict__ bta,
                                                 u16* __restrict__ x2) {
    int wid = threadIdx.x >> 6, lane = threadIdx.x & 63;
    int r = blockIdx.x * 4 + wid;                 // 0..73727
    const float* row = feat + (size_t)r * 128;
    float v0 = row[lane], v1 = row[lane + 64];
    float s = v0 + v1;
    for (int m = 1; m < 64; m <<= 1) s += __shfl_xor(s, m);
    float mean = s * (1.0f / 128.0f);
    float d0 = v0 - mean, d1 = v1 - mean;
    float vs = d0 * d0 + d1 * d1;
    for (int m = 1; m < 64; m <<= 1) vs += __shfl_xor(vs, m);
    float rstd = rsqrtf(vs * (1.0f / 128.0f) + 1e-5f);
    int w = r / 384, rem = r % 384;               // rem = s*192 + h
    int out_r = (rem % 192) * 384 + (rem / 192) * 192 + w;
    u16* orow = x2 + (size_t)out_r * 128;
    orow[lane]      = f2bf(d0 * rstd * g[lane] + bta[lane]);
    orow[lane + 64] = f2bf(d1 * rstd * g[lane + 64] + bta[lane + 64]);
}

// ---------------- pos-embedding projection: P = pos @ w_in[:256].T + b ---------
// qr[e][d][j] = P[d, e*16+j]*0.25 ; kr[e][d][j] = P[d, 128+e*16+j]; row 383 = 0.
__global__ __launch_bounds__(256) void posproj_kernel(const float* __restrict__ pos,
                                                      const float* __restrict__ w_in,
                                                      const float* __restrict__ b_in,
                                                      u16* __restrict__ qr,
                                                      u16* __restrict__ kr) {
    int d = blockIdx.x, t = threadIdx.x;
    if (d == 383) {
        if (t < 128)      { int e = t >> 4,  j = t & 15;  qr[(e * 384 + 383) * 16 + j] = 0; }
        else              { int t2 = t - 128; int e = t2 >> 4, j = t2 & 15; kr[(e * 384 + 383) * 16 + j] = 0; }
        return;
    }
    __shared__ float prow[128];
    if (t < 128) prow[t] = pos[d * 128 + t];
    __syncthreads();
    const float* wrow = w_in + t * 128;
    float acc = b_in[t];
    #pragma unroll 8
    for (int k = 0; k < 128; ++k) acc += prow[k] * wrow[k];
    int which = t >> 7, e = (t >> 4) & 7, j = t & 15;
    if (which == 0) qr[(e * 384 + d) * 16 + j] = f2bf(acc * 0.25f);
    else            kr[(e * 384 + d) * 16 + j] = f2bf(acc);
}

// ---------------- QKV GEMM: [73728,128]bf16 @ w_in^T[128,384] + b -------------
// Output scatter to Q/K/V [batch][head][seq][16] bf16, Q pre-scaled by 0.25.
__global__ __launch_bounds__(256) void qkv_gemm(const u16* __restrict__ X,
                                                const float* __restrict__ Wn,
                                                const float* __restrict__ bias,
                                                u16* __restrict__ Qo,
                                                u16* __restrict__ Ko,
                                                u16* __restrict__ Vo) {
    __shared__ u16 a_lds[128][136];
    __shared__ u16 w_lds[64][136];
    int tid = threadIdx.x;
    int m0 = blockIdx.y * 128, n0 = blockIdx.x * 64;
    #pragma unroll
    for (int i = 0; i < 8; ++i) {
        int idx = tid + 256 * i;
        int row = idx >> 4, c8 = (idx & 15) * 8;
        *(int4*)&a_lds[row][c8] = *(const int4*)&X[(size_t)(m0 + row) * 128 + c8];
    }
    #pragma unroll
    for (int i = 0; i < 8; ++i) {
        int idx = tid + 256 * i;
        int row = idx >> 5, c4 = (idx & 31) * 4;
        float4 f = *(const float4*)&Wn[(size_t)(n0 + row) * 128 + c4];
        uint2 p;
        p.x = (unsigned)f2bf(f.x) | ((unsigned)f2bf(f.y) << 16);
        p.y = (unsigned)f2bf(f.z) | ((unsigned)f2bf(f.w) << 16);
        *(uint2*)&w_lds[row][c4] = p;
    }
    __syncthreads();
    int lane = tid & 63, wid = tid >> 6;
    int wr = (wid >> 1) * 64, wc = (wid & 1) * 32;
    int kg = lane >> 4, l15 = lane & 15;
    f32x4 acc[4][2];
    #pragma unroll
    for (int i = 0; i < 4; ++i)
        #pragma unroll
        for (int j = 0; j < 2; ++j) acc[i][j] = (f32x4){0.f, 0.f, 0.f, 0.f};
    #pragma unroll
    for (int kk = 0; kk < 4; ++kk) {
        int kof = kk * 32 + kg * 8;
        bf16x8 a[4], b[2];
        #pragma unroll
        for (int i = 0; i < 4; ++i) a[i] = *(const bf16x8*)&a_lds[wr + i * 16 + l15][kof];
        #pragma unroll
        for (int j = 0; j < 2; ++j) b[j] = *(const bf16x8*)&w_lds[wc + j * 16 + l15][kof];
        #pragma unroll
        for (int i = 0; i < 4; ++i)
            #pragma unroll
            for (int j = 0; j < 2; ++j)
                acc[i][j] = __builtin_amdgcn_mfma_f32_16x16x32_bf16(a[i], b[j], acc[i][j], 0, 0, 0);
    }
    #pragma unroll
    for (int i = 0; i < 4; ++i)
        #pragma unroll
        for (int j = 0; j < 2; ++j) {
            int col_g = n0 + wc + j * 16 + l15;
            float bv = bias[col_g];
            int which = col_g >> 7, e = (col_g >> 4) & 7, d = col_g & 15;
            u16* dst = which == 0 ? Qo : (which == 1 ? Ko : Vo);
            float scl = which == 0 ? 0.25f : 1.0f;
            #pragma unroll
            for (int ii = 0; ii < 4; ++ii) {
                int row_g = m0 + wr + i * 16 + kg * 4 + ii;
                int batch = row_g % 384, sq = row_g / 384;
                dst[((size_t)(batch * 8 + e) * 192 + sq) * 16 + d] = f2bf((acc[i][j][ii] + bv) * scl);
            }
        }
}

// ---------------- fused rel-pos attention per (batch, head, w-half) -----------
__global__ __launch_bounds__(512) void attn_kernel(const u16* __restrict__ Qg,
                                                   const u16* __restrict__ Kg,
                                                   const u16* __restrict__ Vg,
                                                   const u16* __restrict__ qr_g,
                                                   const u16* __restrict__ kr_g,
                                                   u16* __restrict__ Og) {
    __shared__ float sc[96][196];
    __shared__ u16 Qs[96][24];
    __shared__ u16 Ks[192][24];
    __shared__ u16 Vt[16][200];
    __shared__ u16 krs[384][24];
    __shared__ u16 qrs[384][24];
    __shared__ float rsums[96];
    int tid = threadIdx.x, lane = tid & 63, wid = tid >> 6;
    int half = blockIdx.x, e = blockIdx.y, b = blockIdx.z;
    int w0 = half * 96;
    size_t base = ((size_t)b * 8 + e) * 192 * 16;
    if (tid < 192) { int row = tid >> 1, c8 = (tid & 1) * 8;
        *(int4*)&Qs[row][c8] = *(const int4*)&Qg[base + (size_t)(w0 + row) * 16 + c8]; }
    if (tid < 384) { int row = tid >> 1, c8 = (tid & 1) * 8;
        *(int4*)&Ks[row][c8] = *(const int4*)&Kg[base + (size_t)row * 16 + c8]; }
    #pragma unroll
    for (int i = 0; i < 2; ++i) { int idx = tid + 512 * i; if (idx < 768) {
        int row = idx >> 1, c8 = (idx & 1) * 8;
        *(int4*)&krs[row][c8] = *(const int4*)&kr_g[((size_t)e * 384 + row) * 16 + c8];
        *(int4*)&qrs[row][c8] = *(const int4*)&qr_g[((size_t)e * 384 + row) * 16 + c8]; } }
    #pragma unroll
    for (int i = 0; i < 6; ++i) { int idx = tid + 512 * i;
        int v = idx >> 4, d = idx & 15;
        Vt[d][v] = Vg[base + idx]; }
    __syncthreads();
    int kg = lane >> 4, l15 = lane & 15;
    bool kok = kg < 2;
    // Phase A: content-content  sc[w][v] = Q·K^T
    for (int t = wid; t < 72; t += 8) {
        int wt = t / 12, vt = t % 12;
        int r0 = wt * 16, c0 = vt * 16;
        bf16x8 a = {0,0,0,0,0,0,0,0}, bb = {0,0,0,0,0,0,0,0};
        if (kok) { a = *(const bf16x8*)&Qs[r0 + l15][kg * 8]; bb = *(const bf16x8*)&Ks[c0 + l15][kg * 8]; }
        f32x4 acc = (f32x4){0.f, 0.f, 0.f, 0.f};
        acc = __builtin_amdgcn_mfma_f32_16x16x32_bf16(a, bb, acc, 0, 0, 0);
        #pragma unroll
        for (int ii = 0; ii < 4; ++ii) sc[r0 + kg * 4 + ii][c0 + l15] = acc[ii];
    }
    __syncthreads();
    // Phase B: content-pos  sc[w][v] += (Q·kr^T)[w, w+191-v]
    int tcnt = 0;
    for (int wt = 0; wt < 6; ++wt)
        for (int dd = 0; dd < 24; ++dd) {
            int wt0 = w0 + wt * 16, d0 = dd * 16;
            if (d0 + 15 < wt0 || d0 > wt0 + 206) continue;
            if ((tcnt++ & 7) != wid) continue;
            bf16x8 a = {0,0,0,0,0,0,0,0}, bb = {0,0,0,0,0,0,0,0};
            if (kok) { a = *(const bf16x8*)&Qs[wt * 16 + l15][kg * 8]; bb = *(const bf16x8*)&krs[d0 + l15][kg * 8]; }
            f32x4 acc = (f32x4){0.f, 0.f, 0.f, 0.f};
            acc = __builtin_amdgcn_mfma_f32_16x16x32_bf16(a, bb, acc, 0, 0, 0);
            int d = d0 + l15;
            #pragma unroll
            for (int ii = 0; ii < 4; ++ii) {
                int wl = wt * 16 + kg * 4 + ii;
                int v = (w0 + wl) + 191 - d;
                if (v >= 0 && v < 192) sc[wl][v] += acc[ii];
            }
        }
    __syncthreads();
    // Phase C: pos-content  sc[w][v] += (K·qr^T)[v, w+191-v]
    tcnt = 0;
    for (int vt = 0; vt < 12; ++vt)
        for (int dd = 0; dd < 24; ++dd) {
            int v0 = vt * 16, d0 = dd * 16;
            int lo = v0 + d0 - 191, hi = v0 + 15 + d0 + 15 - 191;
            if (hi < w0 || lo >= w0 + 96) continue;
            if ((tcnt++ & 7) != wid) continue;
            bf16x8 a = {0,0,0,0,0,0,0,0}, bb = {0,0,0,0,0,0,0,0};
            if (kok) { a = *(const bf16x8*)&Ks[v0 + l15][kg * 8]; bb = *(const bf16x8*)&qrs[d0 + l15][kg * 8]; }
            f32x4 acc = (f32x4){0.f, 0.f, 0.f, 0.f};
            acc = __builtin_amdgcn_mfma_f32_16x16x32_bf16(a, bb, acc, 0, 0, 0);
            int d = d0 + l15;
            #pragma unroll
            for (int ii = 0; ii < 4; ++ii) {
                int v = v0 + kg * 4 + ii;
                int w = v + d - 191;
                if (w >= w0 && w < w0 + 96) sc[w - w0][v] += acc[ii];
            }
        }
    __syncthreads();
    // Phase D: softmax rows (exp unnormalized in sc, 1/sum in rsums)
    for (int rr = 0; rr < 12; ++rr) {
        int r = wid * 12 + rr;
        float x0 = sc[r][lane], x1v = sc[r][lane + 64], x2v = sc[r][lane + 128];
        float m = fmaxf(fmaxf(x0, x1v), x2v);
        for (int mm = 1; mm < 64; mm <<= 1) m = fmaxf(m, __shfl_xor(m, mm));
        float e0 = __expf(x0 - m), e1 = __expf(x1v - m), e2 = __expf(x2v - m);
        float s = e0 + e1 + e2;
        for (int mm = 1; mm < 64; mm <<= 1) s += __shfl_xor(s, mm);
        sc[r][lane] = e0; sc[r][lane + 64] = e1; sc[r][lane + 128] = e2;
        if (lane == 0) rsums[r] = 1.0f / s;
    }
    __syncthreads();
    // Phase E: PV, normalize, write O[seq*384+b][e*16+d]
    if (wid < 6) {
        int wt = wid;
        f32x4 acc = (f32x4){0.f, 0.f, 0.f, 0.f};
        for (int kt = 0; kt < 6; ++kt) {
            int k0 = kt * 32;
            float4 p0 = *(const float4*)&sc[wt * 16 + l15][k0 + kg * 8];
            float4 p1 = *(const float4*)&sc[wt * 16 + l15][k0 + kg * 8 + 4];
            bf16x8 a;
            a[0] = (short)f2bf(p0.x); a[1] = (short)f2bf(p0.y);
            a[2] = (short)f2bf(p0.z); a[3] = (short)f2bf(p0.w);
            a[4] = (short)f2bf(p1.x); a[5] = (short)f2bf(p1.y);
            a[6] = (short)f2bf(p1.z); a[7] = (short)f2bf(p1.w);
            bf16x8 bb = *(const bf16x8*)&Vt[l15][k0 + kg * 8];
            acc = __builtin_amdgcn_mfma_f32_16x16x32_bf16(a, bb, acc, 0, 0, 0);
        }
        #pragma unroll
        for (int ii = 0; ii < 4; ++ii) {
            int wl = wt * 16 + kg * 4 + ii;
            float val = acc[ii] * rsums[wl];
            int seq = w0 + wl;
            Og[((size_t)seq * 384 + b) * 128 + e * 16 + l15] = f2bf(val);
        }
    }
}

// ---------------- output projection GEMM -------------------------------------
// MODE 0: x1[(w*384+s*192+h)] = O_row(h*384+s*192+w) @ w_out^T + b   (bf16)
// MODE 1: out[row] = O_row @ w_out^T + b + feat[row]                 (fp32)
template <int MODE>
__global__ __launch_bounds__(256) void outproj_gemm(const u16* __restrict__ X,
                                                    const float* __restrict__ Wn,
                                                    const float* __restrict__ bias,
                                                    const float* __restrict__ feat,
                                                    u16* __restrict__ x1o,
                                                    float* __restrict__ outp) {
    __shared__ u16 a_lds[128][136];
    __shared__ u16 w_lds[64][136];
    int tid = threadIdx.x;
    int m0 = blockIdx.y * 128, n0 = blockIdx.x * 64;
    #pragma unroll
    for (int i = 0; i < 8; ++i) {
        int idx = tid + 256 * i;
        int row = idx >> 4, c8 = (idx & 15) * 8;
        *(int4*)&a_lds[row][c8] = *(const int4*)&X[(size_t)(m0 + row) * 128 + c8];
    }
    #pragma unroll
    for (int i = 0; i < 8; ++i) {
        int idx = tid + 256 * i;
        int row = idx >> 5, c4 = (idx & 31) * 4;
        float4 f = *(const float4*)&Wn[(size_t)(n0 + row) * 128 + c4];
        uint2 p;
        p.x = (unsigned)f2bf(f.x) | ((unsigned)f2bf(f.y) << 16);
        p.y = (unsigned)f2bf(f.z) | ((unsigned)f2bf(f.w) << 16);
        *(uint2*)&w_lds[row][c4] = p;
    }
    __syncthreads();
    int lane = tid & 63, wid = tid >> 6;
    int wr = (wid >> 1) * 64, wc = (wid & 1) * 32;
    int kg = lane >> 4, l15 = lane & 15;
    f32x4 acc[4][2];
    #pragma unroll
    for (int i = 0; i < 4; ++i)
        #pragma unroll
        for (int j = 0; j < 2; ++j) acc[i][j] = (f32x4){0.f, 0.f, 0.f, 0.f};
    #pragma unroll
    for (int kk = 0; kk < 4; ++kk) {
        int kof = kk * 32 + kg * 8;
        bf16x8 a[4], b[2];
        #pragma unroll
        for (int i = 0; i < 4; ++i) a[i] = *(const bf16x8*)&a_lds[wr + i * 16 + l15][kof];
        #pragma unroll
        for (int j = 0; j < 2; ++j) b[j] = *(const bf16x8*)&w_lds[wc + j * 16 + l15][kof];
        #pragma unroll
        for (int i = 0; i < 4; ++i)
            #pragma unroll
            for (int j = 0; j < 2; ++j)
                acc[i][j] = __builtin_amdgcn_mfma_f32_16x16x32_bf16(a[i], b[j], acc[i][j], 0, 0, 0);
    }
    #pragma unroll
    for (int i = 0; i < 4; ++i)
        #pragma unroll
        for (int j = 0; j < 2; ++j) {
            int col_g = n0 + wc + j * 16 + l15;
            float bv = bias[col_g];
            #pragma unroll
            for (int ii = 0; ii < 4; ++ii) {
                int row_g = m0 + wr + i * 16 + kg * 4 + ii;
                float val = acc[i][j][ii] + bv;
                if (MODE == 0) {
                    int h = row_g / 384, rem = row_g % 384, s2 = rem / 192, w = rem % 192;
                    x1o[((size_t)(w * 384 + s2 * 192 + h)) * 128 + col_g] = f2bf(val);
                } else {
                    size_t o = (size_t)row_g * 128 + col_g;
                    outp[o] = val + feat[o];
                }
            }
        }
}

extern "C" void kernel_launch(void* const* d_in, const int* in_sizes, int n_in,
                              void* d_out, int out_size, void* d_ws, size_t ws_size,
                              hipStream_t stream) {
    const float* feat   = (const float*)d_in[0];
    const float* pos    = (const float*)d_in[1];
    const float* pos_y  = (const float*)d_in[2];
    const float* ln_w   = (const float*)d_in[3];
    const float* ln_b   = (const float*)d_in[4];
    const float* w_in1  = (const float*)d_in[5];
    const float* b_in1  = (const float*)d_in[6];
    const float* w_out1 = (const float*)d_in[7];
    const float* b_out1 = (const float*)d_in[8];
    const float* w_in2  = (const float*)d_in[9];
    const float* b_in2  = (const float*)d_in[10];
    const float* w_out2 = (const float*)d_in[11];
    const float* b_out2 = (const float*)d_in[12];
    float* out = (float*)d_out;

    char* ws = (char*)d_ws;
    const size_t R = (size_t)73728 * 128;   // 9,437,184 elements
    u16* x2 = (u16*)ws; ws += R * 2;
    u16* x1 = (u16*)ws; ws += R * 2;
    u16* Q  = (u16*)ws; ws += R * 2;
    u16* K  = (u16*)ws; ws += R * 2;
    u16* V  = (u16*)ws; ws += R * 2;
    u16* O  = (u16*)ws; ws += R * 2;
    u16* qr = (u16*)ws; ws += (size_t)8 * 384 * 16 * 2;
    u16* kr = (u16*)ws; ws += (size_t)8 * 384 * 16 * 2;

    // ---- layer 2 (vertical axis) ----
    ln_kernel<<<18432, 256, 0, stream>>>(feat, ln_w, ln_b, x2);
    posproj_kernel<<<384, 256, 0, stream>>>(pos_y, w_in2, b_in2, qr, kr);
    qkv_gemm<<<dim3(6, 576), 256, 0, stream>>>(x2, w_in2, b_in2, Q, K, V);
    attn_kernel<<<dim3(2, 8, 384), 512, 0, stream>>>(Q, K, V, qr, kr, O);
    outproj_gemm<0><<<dim3(2, 576), 256, 0, stream>>>(O, w_out2, b_out2, nullptr, x1, nullptr);
    // ---- layer 1 (horizontal axis) ----
    posproj_kernel<<<384, 256, 0, stream>>>(pos, w_in1, b_in1, qr, kr);
    qkv_gemm<<<dim3(6, 576), 256, 0, stream>>>(x1, w_in1, b_in1, Q, K, V);
    attn_kernel<<<dim3(2, 8, 384), 512, 0, stream>>>(Q, K, V, qr, kr, O);
    outproj_gemm<1><<<dim3(2, 576), 256, 0, stream>>>(O, w_out1, b_out1, feat, nullptr, out);
}

// Round 2
// 435.019 us; speedup vs baseline: 4.3787x; 4.3787x over previous
//
#include <hip/hip_runtime.h>
#include <hip/hip_bf16.h>

// Axial rel-pos attention, MI355X gfx950.
// Shapes: W=192 seq, B=384 batch (=2*192), C=128, 8 heads, hd=16.

typedef unsigned short u16;
typedef short bf16x8 __attribute__((ext_vector_type(8)));
typedef float f32x4 __attribute__((ext_vector_type(4)));
typedef float f32x16 __attribute__((ext_vector_type(16)));

__device__ inline u16 f2bf(float f) {
    union { float f; unsigned u; } a; a.f = f;
    unsigned u = a.u;
    unsigned r = u + 0x7FFFu + ((u >> 16) & 1u);   // RNE
    return (u16)(r >> 16);
}
__device__ inline float bf2f(u16 x) {
    union { unsigned u; float f; } a; a.u = ((unsigned)x) << 16;
    return a.f;
}

// ---------------- LayerNorm + transpose (feat[w,s*192+h] -> x2[h,s*192+w]) ----
__global__ __launch_bounds__(256) void ln_kernel(const float* __restrict__ feat,
                                                 const float* __restrict__ g,
                                                 const float* __restrict__ bta,
                                                 u16* __restrict__ x2) {
    int wid = threadIdx.x >> 6, lane = threadIdx.x & 63;
    int r = blockIdx.x * 4 + wid;                 // 0..73727
    const float* row = feat + (size_t)r * 128;
    float v0 = row[lane], v1 = row[lane + 64];
    float s = v0 + v1;
    for (int m = 1; m < 64; m <<= 1) s += __shfl_xor(s, m);
    float mean = s * (1.0f / 128.0f);
    float d0 = v0 - mean, d1 = v1 - mean;
    float vs = d0 * d0 + d1 * d1;
    for (int m = 1; m < 64; m <<= 1) vs += __shfl_xor(vs, m);
    float rstd = rsqrtf(vs * (1.0f / 128.0f) + 1e-5f);
    int w = r / 384, rem = r % 384;               // rem = s*192 + h
    int out_r = (rem % 192) * 384 + (rem / 192) * 192 + w;
    u16* orow = x2 + (size_t)out_r * 128;
    orow[lane]      = f2bf(d0 * rstd * g[lane] + bta[lane]);
    orow[lane + 64] = f2bf(d1 * rstd * g[lane + 64] + bta[lane + 64]);
}

// ---------------- pos-embedding projection: P = pos @ w_in[:256].T + b ---------
// qr[e][d][j] = P[d, e*16+j]*0.25 ; kr[e][d][j] = P[d, 128+e*16+j]; row 383 = 0.
__global__ __launch_bounds__(256) void posproj_kernel(const float* __restrict__ pos,
                                                      const float* __restrict__ w_in,
                                                      const float* __restrict__ b_in,
                                                      u16* __restrict__ qr,
                                                      u16* __restrict__ kr) {
    int d = blockIdx.x, t = threadIdx.x;
    if (d == 383) {
        if (t < 128)      { int e = t >> 4,  j = t & 15;  qr[(e * 384 + 383) * 16 + j] = 0; }
        else              { int t2 = t - 128; int e = t2 >> 4, j = t2 & 15; kr[(e * 384 + 383) * 16 + j] = 0; }
        return;
    }
    __shared__ float prow[128];
    if (t < 128) prow[t] = pos[d * 128 + t];
    __syncthreads();
    const float* wrow = w_in + t * 128;
    float acc = b_in[t];
    #pragma unroll 8
    for (int k = 0; k < 128; ++k) acc += prow[k] * wrow[k];
    int which = t >> 7, e = (t >> 4) & 7, j = t & 15;
    if (which == 0) qr[(e * 384 + d) * 16 + j] = f2bf(acc * 0.25f);
    else            kr[(e * 384 + d) * 16 + j] = f2bf(acc);
}

// ---------------- QKV GEMM: [73728,128]bf16 @ w_in^T[128,384] + b -------------
// Output scatter to Q/K/V [batch][head][seq][16] bf16, Q pre-scaled by 0.25.
__global__ __launch_bounds__(256) void qkv_gemm(const u16* __restrict__ X,
                                                const float* __restrict__ Wn,
                                                const float* __restrict__ bias,
                                                u16* __restrict__ Qo,
                                                u16* __restrict__ Ko,
                                                u16* __restrict__ Vo) {
    __shared__ u16 a_lds[128][136];
    __shared__ u16 w_lds[64][136];
    int tid = threadIdx.x;
    int m0 = blockIdx.y * 128, n0 = blockIdx.x * 64;
    #pragma unroll
    for (int i = 0; i < 8; ++i) {
        int idx = tid + 256 * i;
        int row = idx >> 4, c8 = (idx & 15) * 8;
        *(int4*)&a_lds[row][c8] = *(const int4*)&X[(size_t)(m0 + row) * 128 + c8];
    }
    #pragma unroll
    for (int i = 0; i < 8; ++i) {
        int idx = tid + 256 * i;
        int row = idx >> 5, c4 = (idx & 31) * 4;
        float4 f = *(const float4*)&Wn[(size_t)(n0 + row) * 128 + c4];
        uint2 p;
        p.x = (unsigned)f2bf(f.x) | ((unsigned)f2bf(f.y) << 16);
        p.y = (unsigned)f2bf(f.z) | ((unsigned)f2bf(f.w) << 16);
        *(uint2*)&w_lds[row][c4] = p;
    }
    __syncthreads();
    int lane = tid & 63, wid = tid >> 6;
    int wr = (wid >> 1) * 64, wc = (wid & 1) * 32;
    int kg = lane >> 4, l15 = lane & 15;
    f32x4 acc[4][2];
    #pragma unroll
    for (int i = 0; i < 4; ++i)
        #pragma unroll
        for (int j = 0; j < 2; ++j) acc[i][j] = (f32x4){0.f, 0.f, 0.f, 0.f};
    #pragma unroll
    for (int kk = 0; kk < 4; ++kk) {
        int kof = kk * 32 + kg * 8;
        bf16x8 a[4], b[2];
        #pragma unroll
        for (int i = 0; i < 4; ++i) a[i] = *(const bf16x8*)&a_lds[wr + i * 16 + l15][kof];
        #pragma unroll
        for (int j = 0; j < 2; ++j) b[j] = *(const bf16x8*)&w_lds[wc + j * 16 + l15][kof];
        #pragma unroll
        for (int i = 0; i < 4; ++i)
            #pragma unroll
            for (int j = 0; j < 2; ++j)
                acc[i][j] = __builtin_amdgcn_mfma_f32_16x16x32_bf16(a[i], b[j], acc[i][j], 0, 0, 0);
    }
    #pragma unroll
    for (int i = 0; i < 4; ++i)
        #pragma unroll
        for (int j = 0; j < 2; ++j) {
            int col_g = n0 + wc + j * 16 + l15;
            float bv = bias[col_g];
            int which = col_g >> 7, e = (col_g >> 4) & 7, d = col_g & 15;
            u16* dst = which == 0 ? Qo : (which == 1 ? Ko : Vo);
            float scl = which == 0 ? 0.25f : 1.0f;
            #pragma unroll
            for (int ii = 0; ii < 4; ++ii) {
                int row_g = m0 + wr + i * 16 + kg * 4 + ii;
                int batch = row_g % 384, sq = row_g / 384;
                dst[((size_t)(batch * 8 + e) * 192 + sq) * 16 + d] = f2bf((acc[i][j][ii] + bv) * scl);
            }
        }
}

// ---------------- fused rel-pos attention per (batch, head, w-half) -----------
// scores[w][v] = Q[w]·K[v] + Q[w]·kr[w-v+191] + K[v]·qr[w-v+191]
// Phases: A (QK^T, 32x32x16, direct writes) | B (Q·kr^T, scatter +=) |
//         C (qr·K^T, diag scatter +=) | exp | PV (16x16x32 over v).
__global__ __launch_bounds__(512, 6) void attn_kernel(const u16* __restrict__ Qg,
                                                      const u16* __restrict__ Kg,
                                                      const u16* __restrict__ Vg,
                                                      const u16* __restrict__ qr_g,
                                                      const u16* __restrict__ kr_g,
                                                      u16* __restrict__ Og) {
    __shared__ u16 sc[96][200];    // bf16 scores; cols 196..197 hold rsums (f32)
    __shared__ u16 Qs[96][16];
    __shared__ u16 Ks[192][16];
    __shared__ u16 Vt[16][200];
    int tid = threadIdx.x, lane = tid & 63, wid = tid >> 6;
    int half = blockIdx.x, e = blockIdx.y, b = blockIdx.z;
    int w0 = half * 96;
    size_t base = ((size_t)b * 8 + e) * 192 * 16;

    // ---- stage Q (96x16), K (192x16), V^T (16x192) ----
    if (tid < 192) { int row = tid >> 1, h8 = (tid & 1) * 8;
        *(int4*)&Qs[row][h8] = *(const int4*)&Qg[base + (size_t)(w0 + row) * 16 + h8]; }
    if (tid >= 128) { int t2 = tid - 128; int row = t2 >> 1, h8 = (t2 & 1) * 8;
        *(int4*)&Ks[row][h8] = *(const int4*)&Kg[base + (size_t)row * 16 + h8]; }
    #pragma unroll
    for (int i = 0; i < 6; ++i) { int idx = tid + 512 * i;
        Vt[idx & 15][idx >> 4] = Vg[base + idx]; }
    __syncthreads();

    int lo = lane & 31, hi = lane >> 5, hi8 = hi * 8;

    // ---- Phase A: sc[w][v] = Q·K^T  (18 tiles of 32x32) ----
    #pragma unroll
    for (int it = 0; it < 3; ++it) {
        int t = wid + 8 * it;
        if (t < 18) {
            int wt = t / 6, vt = t % 6;
            bf16x8 a  = *(const bf16x8*)&Qs[wt * 32 + lo][hi8];
            bf16x8 bb = *(const bf16x8*)&Ks[vt * 32 + lo][hi8];
            f32x16 acc = {};
            acc = __builtin_amdgcn_mfma_f32_32x32x16_bf16(a, bb, acc, 0, 0, 0);
            #pragma unroll
            for (int ii = 0; ii < 16; ++ii) {
                int row = wt * 32 + (ii & 3) + 8 * (ii >> 2) + 4 * hi;
                sc[row][vt * 32 + lo] = f2bf(acc[ii]);
            }
        }
    }
    __syncthreads();

    // ---- Phase B: sc[w][v] += (Q·kr^T)[w, w+191-v]  (21 tiles) ----
    #pragma unroll
    for (int it = 0; it < 3; ++it) {
        int t = wid + 8 * it;
        if (t < 21) {
            int wt = t / 7, dj = t % 7;
            int d0 = w0 + wt * 32 + dj * 32;          // d0+31 <= 383 always
            bf16x8 a  = *(const bf16x8*)&Qs[wt * 32 + lo][hi8];
            bf16x8 bb = *(const bf16x8*)(kr_g + ((size_t)e * 384 + d0 + lo) * 16 + hi8);
            f32x16 acc = {};
            acc = __builtin_amdgcn_mfma_f32_32x32x16_bf16(a, bb, acc, 0, 0, 0);
            int off = 4 * hi - lo + (wt * 32 + 191 - (dj * 32) - wt * 32);  // v minus rr
            // v = (w0 + w_loc) + 191 - (d0 + lo);  w_loc = wt*32 + rr + 4*hi
            int vbase = w0 + wt * 32 + 191 - d0 - lo + 4 * hi;
            int wlb = wt * 32 + 4 * hi;
            (void)off;
            #pragma unroll
            for (int ii = 0; ii < 16; ++ii) {
                int rr = (ii & 3) + 8 * (ii >> 2);
                int v = vbase + rr;
                if ((unsigned)v < 192u) {
                    u16* p = &sc[wlb + rr][v];
                    *p = f2bf(bf2f(*p) + acc[ii]);
                }
            }
        }
    }
    __syncthreads();

    // ---- Phase C: sc[w][v] += (K[v]·qr[w+191-v])  via qr·K^T tiles (24 tiles) --
    #pragma unroll
    for (int it = 0; it < 3; ++it) {
        int t = wid + 8 * it;
        if (t < 24) {
            int vt = t >> 2, dj = t & 3;
            int V0 = vt * 32;
            int d0 = w0 + 160 - V0 + dj * 32;         // 0 <= d0, d0+31 <= 383
            bf16x8 a  = *(const bf16x8*)(qr_g + ((size_t)e * 384 + d0 + lo) * 16 + hi8);
            bf16x8 bb = *(const bf16x8*)&Ks[V0 + lo][hi8];
            f32x16 acc = {};
            acc = __builtin_amdgcn_mfma_f32_32x32x16_bf16(a, bb, acc, 0, 0, 0);
            int v = V0 + lo;
            int wlb = d0 + 4 * hi + v - 191 - w0;     // wl = wlb + rr
            #pragma unroll
            for (int ii = 0; ii < 16; ++ii) {
                int rr = (ii & 3) + 8 * (ii >> 2);
                int wl = wlb + rr;
                if ((unsigned)wl < 96u) {
                    u16* p = &sc[wl][v];
                    *p = f2bf(bf2f(*p) + acc[ii]);
                }
            }
        }
    }
    __syncthreads();

    // ---- exp pass (no max: logits bounded); rsums packed at sc[r][196] ----
    #pragma unroll
    for (int p = 0; p < 3; ++p) {
        int r = wid * 12 + p * 4 + (lane >> 4);
        int j = lane & 15;
        u16* rowp = &sc[r][j * 12];
        float sum = 0.f;
        #pragma unroll
        for (int k = 0; k < 12; ++k) {
            float ev = __expf(bf2f(rowp[k]));
            sum += ev;
            rowp[k] = f2bf(ev);
        }
        sum += __shfl_xor(sum, 1);
        sum += __shfl_xor(sum, 2);
        sum += __shfl_xor(sum, 4);
        sum += __shfl_xor(sum, 8);
        if (j == 0) *(float*)&sc[r][196] = 1.0f / sum;
    }
    __syncthreads();

    // ---- PV: out[w][c] = sum_v P[w][v] V[v][c]  (16x16x32, K=32 over v) ----
    if (wid < 6) {
        int l15 = lane & 15, kg = lane >> 4;
        f32x4 acc = (f32x4){0.f, 0.f, 0.f, 0.f};
        #pragma unroll
        for (int kt = 0; kt < 6; ++kt) {
            bf16x8 a  = *(const bf16x8*)&sc[wid * 16 + l15][kt * 32 + kg * 8];
            bf16x8 bb = *(const bf16x8*)&Vt[l15][kt * 32 + kg * 8];
            acc = __builtin_amdgcn_mfma_f32_16x16x32_bf16(a, bb, acc, 0, 0, 0);
        }
        #pragma unroll
        for (int ii = 0; ii < 4; ++ii) {
            int wl = wid * 16 + kg * 4 + ii;
            float val = acc[ii] * (*(const float*)&sc[wl][196]);
            Og[((size_t)(w0 + wl) * 384 + b) * 128 + e * 16 + l15] = f2bf(val);
        }
    }
}

// ---------------- output projection GEMM -------------------------------------
// MODE 0: x1[(w*384+s*192+h)] = O_row(h*384+s*192+w) @ w_out^T + b   (bf16)
// MODE 1: out[row] = O_row @ w_out^T + b + feat[row]                 (fp32)
template <int MODE>
__global__ __launch_bounds__(256) void outproj_gemm(const u16* __restrict__ X,
                                                    const float* __restrict__ Wn,
                                                    const float* __restrict__ bias,
                                                    const float* __restrict__ feat,
                                                    u16* __restrict__ x1o,
                                                    float* __restrict__ outp) {
    __shared__ u16 a_lds[128][136];
    __shared__ u16 w_lds[64][136];
    int tid = threadIdx.x;
    int m0 = blockIdx.y * 128, n0 = blockIdx.x * 64;
    #pragma unroll
    for (int i = 0; i < 8; ++i) {
        int idx = tid + 256 * i;
        int row = idx >> 4, c8 = (idx & 15) * 8;
        *(int4*)&a_lds[row][c8] = *(const int4*)&X[(size_t)(m0 + row) * 128 + c8];
    }
    #pragma unroll
    for (int i = 0; i < 8; ++i) {
        int idx = tid + 256 * i;
        int row = idx >> 5, c4 = (idx & 31) * 4;
        float4 f = *(const float4*)&Wn[(size_t)(n0 + row) * 128 + c4];
        uint2 p;
        p.x = (unsigned)f2bf(f.x) | ((unsigned)f2bf(f.y) << 16);
        p.y = (unsigned)f2bf(f.z) | ((unsigned)f2bf(f.w) << 16);
        *(uint2*)&w_lds[row][c4] = p;
    }
    __syncthreads();
    int lane = tid & 63, wid = tid >> 6;
    int wr = (wid >> 1) * 64, wc = (wid & 1) * 32;
    int kg = lane >> 4, l15 = lane & 15;
    f32x4 acc[4][2];
    #pragma unroll
    for (int i = 0; i < 4; ++i)
        #pragma unroll
        for (int j = 0; j < 2; ++j) acc[i][j] = (f32x4){0.f, 0.f, 0.f, 0.f};
    #pragma unroll
    for (int kk = 0; kk < 4; ++kk) {
        int kof = kk * 32 + kg * 8;
        bf16x8 a[4], b[2];
        #pragma unroll
        for (int i = 0; i < 4; ++i) a[i] = *(const bf16x8*)&a_lds[wr + i * 16 + l15][kof];
        #pragma unroll
        for (int j = 0; j < 2; ++j) b[j] = *(const bf16x8*)&w_lds[wc + j * 16 + l15][kof];
        #pragma unroll
        for (int i = 0; i < 4; ++i)
            #pragma unroll
            for (int j = 0; j < 2; ++j)
                acc[i][j] = __builtin_amdgcn_mfma_f32_16x16x32_bf16(a[i], b[j], acc[i][j], 0, 0, 0);
    }
    #pragma unroll
    for (int i = 0; i < 4; ++i)
        #pragma unroll
        for (int j = 0; j < 2; ++j) {
            int col_g = n0 + wc + j * 16 + l15;
            float bv = bias[col_g];
            #pragma unroll
            for (int ii = 0; ii < 4; ++ii) {
                int row_g = m0 + wr + i * 16 + kg * 4 + ii;
                float val = acc[i][j][ii] + bv;
                if (MODE == 0) {
                    int h = row_g / 384, rem = row_g % 384, s2 = rem / 192, w = rem % 192;
                    x1o[((size_t)(w * 384 + s2 * 192 + h)) * 128 + col_g] = f2bf(val);
                } else {
                    size_t o = (size_t)row_g * 128 + col_g;
                    outp[o] = val + feat[o];
                }
            }
        }
}

extern "C" void kernel_launch(void* const* d_in, const int* in_sizes, int n_in,
                              void* d_out, int out_size, void* d_ws, size_t ws_size,
                              hipStream_t stream) {
    const float* feat   = (const float*)d_in[0];
    const float* pos    = (const float*)d_in[1];
    const float* pos_y  = (const float*)d_in[2];
    const float* ln_w   = (const float*)d_in[3];
    const float* ln_b   = (const float*)d_in[4];
    const float* w_in1  = (const float*)d_in[5];
    const float* b_in1  = (const float*)d_in[6];
    const float* w_out1 = (const float*)d_in[7];
    const float* b_out1 = (const float*)d_in[8];
    const float* w_in2  = (const float*)d_in[9];
    const float* b_in2  = (const float*)d_in[10];
    const float* w_out2 = (const float*)d_in[11];
    const float* b_out2 = (const float*)d_in[12];
    float* out = (float*)d_out;

    char* ws = (char*)d_ws;
    const size_t R = (size_t)73728 * 128;   // 9,437,184 elements
    u16* x2 = (u16*)ws; ws += R * 2;
    u16* x1 = (u16*)ws; ws += R * 2;
    u16* Q  = (u16*)ws; ws += R * 2;
    u16* K  = (u16*)ws; ws += R * 2;
    u16* V  = (u16*)ws; ws += R * 2;
    u16* O  = (u16*)ws; ws += R * 2;
    u16* qr = (u16*)ws; ws += (size_t)8 * 384 * 16 * 2;
    u16* kr = (u16*)ws; ws += (size_t)8 * 384 * 16 * 2;

    // ---- layer 2 (vertical axis) ----
    ln_kernel<<<18432, 256, 0, stream>>>(feat, ln_w, ln_b, x2);
    posproj_kernel<<<384, 256, 0, stream>>>(pos_y, w_in2, b_in2, qr, kr);
    qkv_gemm<<<dim3(6, 576), 256, 0, stream>>>(x2, w_in2, b_in2, Q, K, V);
    attn_kernel<<<dim3(2, 8, 384), 512, 0, stream>>>(Q, K, V, qr, kr, O);
    outproj_gemm<0><<<dim3(2, 576), 256, 0, stream>>>(O, w_out2, b_out2, nullptr, x1, nullptr);
    // ---- layer 1 (horizontal axis) ----
    posproj_kernel<<<384, 256, 0, stream>>>(pos, w_in1, b_in1, qr, kr);
    qkv_gemm<<<dim3(6, 576), 256, 0, stream>>>(x1, w_in1, b_in1, Q, K, V);
    attn_kernel<<<dim3(2, 8, 384), 512, 0, stream>>>(Q, K, V, qr, kr, O);
    outproj_gemm<1><<<dim3(2, 576), 256, 0, stream>>>(O, w_out1, b_out1, feat, nullptr, out);
}

// Round 3
// 363.589 us; speedup vs baseline: 5.2390x; 1.1965x over previous
//
#include <hip/hip_runtime.h>
#include <hip/hip_bf16.h>

// Axial rel-pos attention, MI355X gfx950.
// Shapes: W=192 seq, B=384 batch (=2*192), C=128, 8 heads, hd=16.

typedef unsigned short u16;
typedef short bf16x4 __attribute__((ext_vector_type(4)));
typedef short bf16x8 __attribute__((ext_vector_type(8)));
typedef float f32x4 __attribute__((ext_vector_type(4)));
typedef float f32x16 __attribute__((ext_vector_type(16)));

__device__ inline u16 f2bf(float f) {
    union { float f; unsigned u; } a; a.f = f;
    unsigned u = a.u;
    unsigned r = u + 0x7FFFu + ((u >> 16) & 1u);   // RNE
    return (u16)(r >> 16);
}
__device__ inline float bf2f(u16 x) {
    union { unsigned u; float f; } a; a.u = ((unsigned)x) << 16;
    return a.f;
}

// ---------------- LayerNorm + transpose (feat[w,s*192+h] -> x2[h,s*192+w]) ----
__global__ __launch_bounds__(256) void ln_kernel(const float* __restrict__ feat,
                                                 const float* __restrict__ g,
                                                 const float* __restrict__ bta,
                                                 u16* __restrict__ x2) {
    int wid = threadIdx.x >> 6, lane = threadIdx.x & 63;
    int r = blockIdx.x * 4 + wid;                 // 0..73727
    const float* row = feat + (size_t)r * 128;
    float v0 = row[lane], v1 = row[lane + 64];
    float s = v0 + v1;
    for (int m = 1; m < 64; m <<= 1) s += __shfl_xor(s, m);
    float mean = s * (1.0f / 128.0f);
    float d0 = v0 - mean, d1 = v1 - mean;
    float vs = d0 * d0 + d1 * d1;
    for (int m = 1; m < 64; m <<= 1) vs += __shfl_xor(vs, m);
    float rstd = rsqrtf(vs * (1.0f / 128.0f) + 1e-5f);
    int w = r / 384, rem = r % 384;               // rem = s*192 + h
    int out_r = (rem % 192) * 384 + (rem / 192) * 192 + w;
    u16* orow = x2 + (size_t)out_r * 128;
    orow[lane]      = f2bf(d0 * rstd * g[lane] + bta[lane]);
    orow[lane + 64] = f2bf(d1 * rstd * g[lane + 64] + bta[lane + 64]);
}

// ---------------- pos-embedding projection: P = pos @ w_in[:256].T + b ---------
// qr[e][d][j] = P[d, e*16+j]*0.25 ; kr[e][d][j] = P[d, 128+e*16+j]; row 383 = 0.
__global__ __launch_bounds__(256) void posproj_kernel(const float* __restrict__ pos,
                                                      const float* __restrict__ w_in,
                                                      const float* __restrict__ b_in,
                                                      u16* __restrict__ qr,
                                                      u16* __restrict__ kr) {
    int d = blockIdx.x, t = threadIdx.x;
    if (d == 383) {
        if (t < 128)      { int e = t >> 4,  j = t & 15;  qr[(e * 384 + 383) * 16 + j] = 0; }
        else              { int t2 = t - 128; int e = t2 >> 4, j = t2 & 15; kr[(e * 384 + 383) * 16 + j] = 0; }
        return;
    }
    __shared__ float prow[128];
    if (t < 128) prow[t] = pos[d * 128 + t];
    __syncthreads();
    const float* wrow = w_in + t * 128;
    float acc = b_in[t];
    #pragma unroll 8
    for (int k = 0; k < 128; ++k) acc += prow[k] * wrow[k];
    int which = t >> 7, e = (t >> 4) & 7, j = t & 15;
    if (which == 0) qr[(e * 384 + d) * 16 + j] = f2bf(acc * 0.25f);
    else            kr[(e * 384 + d) * 16 + j] = f2bf(acc);
}

// ---------------- QKV GEMM: [73728,128]bf16 @ w_in^T[128,384] + b -------------
// Output scatter to Q/K/V [batch][head][seq][16] bf16, Q pre-scaled by 0.25.
__global__ __launch_bounds__(256) void qkv_gemm(const u16* __restrict__ X,
                                                const float* __restrict__ Wn,
                                                const float* __restrict__ bias,
                                                u16* __restrict__ Qo,
                                                u16* __restrict__ Ko,
                                                u16* __restrict__ Vo) {
    __shared__ u16 a_lds[128][136];
    __shared__ u16 w_lds[64][136];
    int tid = threadIdx.x;
    int m0 = blockIdx.y * 128, n0 = blockIdx.x * 64;
    #pragma unroll
    for (int i = 0; i < 8; ++i) {
        int idx = tid + 256 * i;
        int row = idx >> 4, c8 = (idx & 15) * 8;
        *(int4*)&a_lds[row][c8] = *(const int4*)&X[(size_t)(m0 + row) * 128 + c8];
    }
    #pragma unroll
    for (int i = 0; i < 8; ++i) {
        int idx = tid + 256 * i;
        int row = idx >> 5, c4 = (idx & 31) * 4;
        float4 f = *(const float4*)&Wn[(size_t)(n0 + row) * 128 + c4];
        uint2 p;
        p.x = (unsigned)f2bf(f.x) | ((unsigned)f2bf(f.y) << 16);
        p.y = (unsigned)f2bf(f.z) | ((unsigned)f2bf(f.w) << 16);
        *(uint2*)&w_lds[row][c4] = p;
    }
    __syncthreads();
    int lane = tid & 63, wid = tid >> 6;
    int wr = (wid >> 1) * 64, wc = (wid & 1) * 32;
    int kg = lane >> 4, l15 = lane & 15;
    f32x4 acc[4][2];
    #pragma unroll
    for (int i = 0; i < 4; ++i)
        #pragma unroll
        for (int j = 0; j < 2; ++j) acc[i][j] = (f32x4){0.f, 0.f, 0.f, 0.f};
    #pragma unroll
    for (int kk = 0; kk < 4; ++kk) {
        int kof = kk * 32 + kg * 8;
        bf16x8 a[4], b[2];
        #pragma unroll
        for (int i = 0; i < 4; ++i) a[i] = *(const bf16x8*)&a_lds[wr + i * 16 + l15][kof];
        #pragma unroll
        for (int j = 0; j < 2; ++j) b[j] = *(const bf16x8*)&w_lds[wc + j * 16 + l15][kof];
        #pragma unroll
        for (int i = 0; i < 4; ++i)
            #pragma unroll
            for (int j = 0; j < 2; ++j)
                acc[i][j] = __builtin_amdgcn_mfma_f32_16x16x32_bf16(a[i], b[j], acc[i][j], 0, 0, 0);
    }
    #pragma unroll
    for (int i = 0; i < 4; ++i)
        #pragma unroll
        for (int j = 0; j < 2; ++j) {
            int col_g = n0 + wc + j * 16 + l15;
            float bv = bias[col_g];
            int which = col_g >> 7, e = (col_g >> 4) & 7, d = col_g & 15;
            u16* dst = which == 0 ? Qo : (which == 1 ? Ko : Vo);
            float scl = which == 0 ? 0.25f : 1.0f;
            #pragma unroll
            for (int ii = 0; ii < 4; ++ii) {
                int row_g = m0 + wr + i * 16 + kg * 4 + ii;
                int batch = row_g % 384, sq = row_g / 384;
                dst[((size_t)(batch * 8 + e) * 192 + sq) * 16 + d] = f2bf((acc[i][j][ii] + bv) * scl);
            }
        }
}

// ---------------- fused rel-pos attention per (batch, head, w-half) -----------
// scores[w][v] = Q[w]·K[v] + Q[w]·kr[w-v+191] + K[v]·qr[w-v+191]
// fp32 score buffer; Q/K/kr/qr operands read straight from global (L2-hot).
// sc cols: 0..191 scores, 192 dummy (OOB clamp target), 193 rsums.
__global__ __launch_bounds__(512, 4) void attn_kernel(const u16* __restrict__ Qg,
                                                      const u16* __restrict__ Kg,
                                                      const u16* __restrict__ Vg,
                                                      const u16* __restrict__ qr_g,
                                                      const u16* __restrict__ kr_g,
                                                      u16* __restrict__ Og) {
    __shared__ float sc[96][194];   // 74496 B
    __shared__ u16 Vt[16][200];     // 6400 B
    int tid = threadIdx.x, lane = tid & 63, wid = tid >> 6;
    int half = blockIdx.x, e = blockIdx.y, b = blockIdx.z;
    int w0 = half * 96;
    size_t base = ((size_t)b * 8 + e) * 192 * 16;

    // stage V^T (16 x 192)
    #pragma unroll
    for (int i = 0; i < 6; ++i) { int idx = tid + 512 * i;
        Vt[idx & 15][idx >> 4] = Vg[base + idx]; }

    int lo = lane & 31, hi = lane >> 5, hi8 = hi * 8;
    const u16* Qrow  = Qg + base;
    const u16* Krow  = Kg + base;
    const u16* krrow = kr_g + (size_t)e * 384 * 16;
    const u16* qrrow = qr_g + (size_t)e * 384 * 16;

    // ---- Phase A: sc[w][v] = Q·K^T  (18 tiles of 32x32) ----
    #pragma unroll
    for (int it = 0; it < 3; ++it) {
        int t = wid + 8 * it;
        if (t < 18) {
            int wt = t / 6, vt = t % 6;
            bf16x8 a  = *(const bf16x8*)(Qrow + (size_t)(w0 + wt * 32 + lo) * 16 + hi8);
            bf16x8 bb = *(const bf16x8*)(Krow + (size_t)(vt * 32 + lo) * 16 + hi8);
            f32x16 acc = {};
            acc = __builtin_amdgcn_mfma_f32_32x32x16_bf16(a, bb, acc, 0, 0, 0);
            #pragma unroll
            for (int ii = 0; ii < 16; ++ii) {
                int row = wt * 32 + (ii & 3) + 8 * (ii >> 2) + 4 * hi;
                sc[row][vt * 32 + lo] = acc[ii];
            }
        }
    }
    __syncthreads();

    // ---- Phase B: sc[w][v] += (Q·kr^T)[w, w+191-v]  (21 tiles) ----
    #pragma unroll
    for (int it = 0; it < 3; ++it) {
        int t = wid + 8 * it;
        if (t < 21) {
            int wt = t / 7, dj = t % 7;
            int d0 = w0 + wt * 32 + dj * 32;          // 0 <= d0, d0+31 <= 383
            bf16x8 a  = *(const bf16x8*)(Qrow + (size_t)(w0 + wt * 32 + lo) * 16 + hi8);
            bf16x8 bb = *(const bf16x8*)(krrow + (size_t)(d0 + lo) * 16 + hi8);
            f32x16 acc = {};
            acc = __builtin_amdgcn_mfma_f32_32x32x16_bf16(a, bb, acc, 0, 0, 0);
            int vbase = w0 + wt * 32 + 191 - d0 - lo + 4 * hi;
            int wlb = wt * 32 + 4 * hi;
            #pragma unroll
            for (int ii = 0; ii < 16; ++ii) {
                int rr = (ii & 3) + 8 * (ii >> 2);
                int v = vbase + rr;
                int col = ((unsigned)v < 192u) ? v : 192;   // clamp to dummy col
                sc[wlb + rr][col] += acc[ii];
            }
        }
    }
    __syncthreads();

    // ---- Phase C: sc[w][v] += K[v]·qr[w+191-v]  via qr·K^T tiles (24) ----
    #pragma unroll
    for (int it = 0; it < 3; ++it) {
        int t = wid + 8 * it;
        if (t < 24) {
            int vt = t >> 2, dj = t & 3;
            int V0 = vt * 32;
            int d0 = w0 + 160 - V0 + dj * 32;         // 0 <= d0, d0+31 <= 383
            bf16x8 a  = *(const bf16x8*)(qrrow + (size_t)(d0 + lo) * 16 + hi8);
            bf16x8 bb = *(const bf16x8*)(Krow + (size_t)(V0 + lo) * 16 + hi8);
            f32x16 acc = {};
            acc = __builtin_amdgcn_mfma_f32_32x32x16_bf16(a, bb, acc, 0, 0, 0);
            int v = V0 + lo;
            int wlb = d0 + 4 * hi + v - 191 - w0;     // wl = wlb + rr
            #pragma unroll
            for (int ii = 0; ii < 16; ++ii) {
                int rr = (ii & 3) + 8 * (ii >> 2);
                int wl = wlb + rr;
                float* p = ((unsigned)wl < 96u) ? &sc[wl][v] : &sc[0][192];
                *p += acc[ii];
            }
        }
    }
    __syncthreads();

    // ---- exp pass: f32 in -> packed bf16 (row low half); rsum -> col 193 ----
    #pragma unroll
    for (int p = 0; p < 3; ++p) {
        int r = wid * 12 + p * 4 + (lane >> 4);
        int j = lane & 15;
        float x[12];
        #pragma unroll
        for (int k = 0; k < 6; ++k)
            *(float2*)&x[k * 2] = *(const float2*)&sc[r][j * 12 + k * 2];
        float sum = 0.f;
        #pragma unroll
        for (int k = 0; k < 12; ++k) { x[k] = __expf(x[k]); sum += x[k]; }
        unsigned* prow32 = (unsigned*)&sc[r][0];
        #pragma unroll
        for (int k = 0; k < 6; ++k)
            prow32[j * 6 + k] = (unsigned)f2bf(x[2 * k]) | ((unsigned)f2bf(x[2 * k + 1]) << 16);
        sum += __shfl_xor(sum, 1);
        sum += __shfl_xor(sum, 2);
        sum += __shfl_xor(sum, 4);
        sum += __shfl_xor(sum, 8);
        if (j == 0) sc[r][193] = 1.0f / sum;
    }
    __syncthreads();

    // ---- PV: out[w][c] = sum_v P[w][v] V[v][c]  (16x16x32 over v) ----
    if (wid < 6) {
        int l15 = lane & 15, kg = lane >> 4;
        const u16* prow = (const u16*)&sc[wid * 16 + l15][0];   // packed bf16 row
        f32x4 acc = (f32x4){0.f, 0.f, 0.f, 0.f};
        #pragma unroll
        for (int kt = 0; kt < 6; ++kt) {
            bf16x4 a0 = *(const bf16x4*)(prow + kt * 32 + kg * 8);
            bf16x4 a1 = *(const bf16x4*)(prow + kt * 32 + kg * 8 + 4);
            bf16x8 a;
            a[0] = a0[0]; a[1] = a0[1]; a[2] = a0[2]; a[3] = a0[3];
            a[4] = a1[0]; a[5] = a1[1]; a[6] = a1[2]; a[7] = a1[3];
            bf16x8 bb = *(const bf16x8*)&Vt[l15][kt * 32 + kg * 8];
            acc = __builtin_amdgcn_mfma_f32_16x16x32_bf16(a, bb, acc, 0, 0, 0);
        }
        #pragma unroll
        for (int ii = 0; ii < 4; ++ii) {
            int wl = wid * 16 + kg * 4 + ii;
            float val = acc[ii] * sc[wl][193];
            Og[((size_t)(w0 + wl) * 384 + b) * 128 + e * 16 + l15] = f2bf(val);
        }
    }
}

// ---------------- output projection GEMM -------------------------------------
// MODE 0: x1[(w*384+s*192+h)] = O_row(h*384+s*192+w) @ w_out^T + b   (bf16)
// MODE 1: out[row] = O_row @ w_out^T + b + feat[row]                 (fp32)
template <int MODE>
__global__ __launch_bounds__(256) void outproj_gemm(const u16* __restrict__ X,
                                                    const float* __restrict__ Wn,
                                                    const float* __restrict__ bias,
                                                    const float* __restrict__ feat,
                                                    u16* __restrict__ x1o,
                                                    float* __restrict__ outp) {
    __shared__ u16 a_lds[128][136];
    __shared__ u16 w_lds[64][136];
    int tid = threadIdx.x;
    int m0 = blockIdx.y * 128, n0 = blockIdx.x * 64;
    #pragma unroll
    for (int i = 0; i < 8; ++i) {
        int idx = tid + 256 * i;
        int row = idx >> 4, c8 = (idx & 15) * 8;
        *(int4*)&a_lds[row][c8] = *(const int4*)&X[(size_t)(m0 + row) * 128 + c8];
    }
    #pragma unroll
    for (int i = 0; i < 8; ++i) {
        int idx = tid + 256 * i;
        int row = idx >> 5, c4 = (idx & 31) * 4;
        float4 f = *(const float4*)&Wn[(size_t)(n0 + row) * 128 + c4];
        uint2 p;
        p.x = (unsigned)f2bf(f.x) | ((unsigned)f2bf(f.y) << 16);
        p.y = (unsigned)f2bf(f.z) | ((unsigned)f2bf(f.w) << 16);
        *(uint2*)&w_lds[row][c4] = p;
    }
    __syncthreads();
    int lane = tid & 63, wid = tid >> 6;
    int wr = (wid >> 1) * 64, wc = (wid & 1) * 32;
    int kg = lane >> 4, l15 = lane & 15;
    f32x4 acc[4][2];
    #pragma unroll
    for (int i = 0; i < 4; ++i)
        #pragma unroll
        for (int j = 0; j < 2; ++j) acc[i][j] = (f32x4){0.f, 0.f, 0.f, 0.f};
    #pragma unroll
    for (int kk = 0; kk < 4; ++kk) {
        int kof = kk * 32 + kg * 8;
        bf16x8 a[4], b[2];
        #pragma unroll
        for (int i = 0; i < 4; ++i) a[i] = *(const bf16x8*)&a_lds[wr + i * 16 + l15][kof];
        #pragma unroll
        for (int j = 0; j < 2; ++j) b[j] = *(const bf16x8*)&w_lds[wc + j * 16 + l15][kof];
        #pragma unroll
        for (int i = 0; i < 4; ++i)
            #pragma unroll
            for (int j = 0; j < 2; ++j)
                acc[i][j] = __builtin_amdgcn_mfma_f32_16x16x32_bf16(a[i], b[j], acc[i][j], 0, 0, 0);
    }
    #pragma unroll
    for (int i = 0; i < 4; ++i)
        #pragma unroll
        for (int j = 0; j < 2; ++j) {
            int col_g = n0 + wc + j * 16 + l15;
            float bv = bias[col_g];
            #pragma unroll
            for (int ii = 0; ii < 4; ++ii) {
                int row_g = m0 + wr + i * 16 + kg * 4 + ii;
                float val = acc[i][j][ii] + bv;
                if (MODE == 0) {
                    int h = row_g / 384, rem = row_g % 384, s2 = rem / 192, w = rem % 192;
                    x1o[((size_t)(w * 384 + s2 * 192 + h)) * 128 + col_g] = f2bf(val);
                } else {
                    size_t o = (size_t)row_g * 128 + col_g;
                    outp[o] = val + feat[o];
                }
            }
        }
}

extern "C" void kernel_launch(void* const* d_in, const int* in_sizes, int n_in,
                              void* d_out, int out_size, void* d_ws, size_t ws_size,
                              hipStream_t stream) {
    const float* feat   = (const float*)d_in[0];
    const float* pos    = (const float*)d_in[1];
    const float* pos_y  = (const float*)d_in[2];
    const float* ln_w   = (const float*)d_in[3];
    const float* ln_b   = (const float*)d_in[4];
    const float* w_in1  = (const float*)d_in[5];
    const float* b_in1  = (const float*)d_in[6];
    const float* w_out1 = (const float*)d_in[7];
    const float* b_out1 = (const float*)d_in[8];
    const float* w_in2  = (const float*)d_in[9];
    const float* b_in2  = (const float*)d_in[10];
    const float* w_out2 = (const float*)d_in[11];
    const float* b_out2 = (const float*)d_in[12];
    float* out = (float*)d_out;

    char* ws = (char*)d_ws;
    const size_t R = (size_t)73728 * 128;   // 9,437,184 elements
    u16* x2 = (u16*)ws; ws += R * 2;
    u16* x1 = (u16*)ws; ws += R * 2;
    u16* Q  = (u16*)ws; ws += R * 2;
    u16* K  = (u16*)ws; ws += R * 2;
    u16* V  = (u16*)ws; ws += R * 2;
    u16* O  = (u16*)ws; ws += R * 2;
    u16* qr = (u16*)ws; ws += (size_t)8 * 384 * 16 * 2;
    u16* kr = (u16*)ws; ws += (size_t)8 * 384 * 16 * 2;

    // ---- layer 2 (vertical axis) ----
    ln_kernel<<<18432, 256, 0, stream>>>(feat, ln_w, ln_b, x2);
    posproj_kernel<<<384, 256, 0, stream>>>(pos_y, w_in2, b_in2, qr, kr);
    qkv_gemm<<<dim3(6, 576), 256, 0, stream>>>(x2, w_in2, b_in2, Q, K, V);
    attn_kernel<<<dim3(2, 8, 384), 512, 0, stream>>>(Q, K, V, qr, kr, O);
    outproj_gemm<0><<<dim3(2, 576), 256, 0, stream>>>(O, w_out2, b_out2, nullptr, x1, nullptr);
    // ---- layer 1 (horizontal axis) ----
    posproj_kernel<<<384, 256, 0, stream>>>(pos, w_in1, b_in1, qr, kr);
    qkv_gemm<<<dim3(6, 576), 256, 0, stream>>>(x1, w_in1, b_in1, Q, K, V);
    attn_kernel<<<dim3(2, 8, 384), 512, 0, stream>>>(Q, K, V, qr, kr, O);
    outproj_gemm<1><<<dim3(2, 576), 256, 0, stream>>>(O, w_out1, b_out1, feat, nullptr, out);
}

// Round 4
// 356.480 us; speedup vs baseline: 5.3434x; 1.0199x over previous
//
#include <hip/hip_runtime.h>
#include <hip/hip_bf16.h>

// Axial rel-pos attention, MI355X gfx950.
// Shapes: W=192 seq, B=384 batch (=2*192), C=128, 8 heads, hd=16.

typedef unsigned short u16;
typedef short bf16x8 __attribute__((ext_vector_type(8)));
typedef float f32x4 __attribute__((ext_vector_type(4)));
typedef float f32x16 __attribute__((ext_vector_type(16)));

__device__ inline u16 f2bf(float f) {
    union { float f; unsigned u; } a; a.f = f;
    unsigned u = a.u;
    unsigned r = u + 0x7FFFu + ((u >> 16) & 1u);   // RNE
    return (u16)(r >> 16);
}
__device__ inline unsigned cvt_pk_bf16(float lo, float hi) {
    unsigned r;
    asm("v_cvt_pk_bf16_f32 %0, %1, %2" : "=v"(r) : "v"(lo), "v"(hi));
    return r;
}

// ---------------- LayerNorm + transpose (feat[w,s*192+h] -> x2[h,s*192+w]) ----
__global__ __launch_bounds__(256) void ln_kernel(const float* __restrict__ feat,
                                                 const float* __restrict__ g,
                                                 const float* __restrict__ bta,
                                                 u16* __restrict__ x2) {
    int wid = threadIdx.x >> 6, lane = threadIdx.x & 63;
    int r = blockIdx.x * 4 + wid;                 // 0..73727
    const float* row = feat + (size_t)r * 128;
    float v0 = row[lane], v1 = row[lane + 64];
    float s = v0 + v1;
    for (int m = 1; m < 64; m <<= 1) s += __shfl_xor(s, m);
    float mean = s * (1.0f / 128.0f);
    float d0 = v0 - mean, d1 = v1 - mean;
    float vs = d0 * d0 + d1 * d1;
    for (int m = 1; m < 64; m <<= 1) vs += __shfl_xor(vs, m);
    float rstd = rsqrtf(vs * (1.0f / 128.0f) + 1e-5f);
    int w = r / 384, rem = r % 384;               // rem = s*192 + h
    int out_r = (rem % 192) * 384 + (rem / 192) * 192 + w;
    u16* orow = x2 + (size_t)out_r * 128;
    orow[lane]      = f2bf(d0 * rstd * g[lane] + bta[lane]);
    orow[lane + 64] = f2bf(d1 * rstd * g[lane + 64] + bta[lane + 64]);
}

// ---------------- pos-embedding projection: P = pos @ w_in[:256].T + b ---------
// qr[e][d][j] = P[d, e*16+j]*0.25 ; kr[e][d][j] = P[d, 128+e*16+j]; row 383 = 0.
__global__ __launch_bounds__(256) void posproj_kernel(const float* __restrict__ pos,
                                                      const float* __restrict__ w_in,
                                                      const float* __restrict__ b_in,
                                                      u16* __restrict__ qr,
                                                      u16* __restrict__ kr) {
    int d = blockIdx.x, t = threadIdx.x;
    if (d == 383) {
        if (t < 128)      { int e = t >> 4,  j = t & 15;  qr[(e * 384 + 383) * 16 + j] = 0; }
        else              { int t2 = t - 128; int e = t2 >> 4, j = t2 & 15; kr[(e * 384 + 383) * 16 + j] = 0; }
        return;
    }
    __shared__ float prow[128];
    if (t < 128) prow[t] = pos[d * 128 + t];
    __syncthreads();
    const float* wrow = w_in + t * 128;
    float acc = b_in[t];
    #pragma unroll 8
    for (int k = 0; k < 128; ++k) acc += prow[k] * wrow[k];
    int which = t >> 7, e = (t >> 4) & 7, j = t & 15;
    if (which == 0) qr[(e * 384 + d) * 16 + j] = f2bf(acc * 0.25f);
    else            kr[(e * 384 + d) * 16 + j] = f2bf(acc);
}

// ---------------- QKV GEMM: [73728,128]bf16 @ w_in^T[128,384] + b -------------
// Output scatter to Q/K/V [batch][head][seq][16] bf16, Q pre-scaled by 0.25.
__global__ __launch_bounds__(256) void qkv_gemm(const u16* __restrict__ X,
                                                const float* __restrict__ Wn,
                                                const float* __restrict__ bias,
                                                u16* __restrict__ Qo,
                                                u16* __restrict__ Ko,
                                                u16* __restrict__ Vo) {
    __shared__ u16 a_lds[128][136];
    __shared__ u16 w_lds[64][136];
    int tid = threadIdx.x;
    int m0 = blockIdx.y * 128, n0 = blockIdx.x * 64;
    #pragma unroll
    for (int i = 0; i < 8; ++i) {
        int idx = tid + 256 * i;
        int row = idx >> 4, c8 = (idx & 15) * 8;
        *(int4*)&a_lds[row][c8] = *(const int4*)&X[(size_t)(m0 + row) * 128 + c8];
    }
    #pragma unroll
    for (int i = 0; i < 8; ++i) {
        int idx = tid + 256 * i;
        int row = idx >> 5, c4 = (idx & 31) * 4;
        float4 f = *(const float4*)&Wn[(size_t)(n0 + row) * 128 + c4];
        uint2 p;
        p.x = (unsigned)f2bf(f.x) | ((unsigned)f2bf(f.y) << 16);
        p.y = (unsigned)f2bf(f.z) | ((unsigned)f2bf(f.w) << 16);
        *(uint2*)&w_lds[row][c4] = p;
    }
    __syncthreads();
    int lane = tid & 63, wid = tid >> 6;
    int wr = (wid >> 1) * 64, wc = (wid & 1) * 32;
    int kg = lane >> 4, l15 = lane & 15;
    f32x4 acc[4][2];
    #pragma unroll
    for (int i = 0; i < 4; ++i)
        #pragma unroll
        for (int j = 0; j < 2; ++j) acc[i][j] = (f32x4){0.f, 0.f, 0.f, 0.f};
    #pragma unroll
    for (int kk = 0; kk < 4; ++kk) {
        int kof = kk * 32 + kg * 8;
        bf16x8 a[4], b[2];
        #pragma unroll
        for (int i = 0; i < 4; ++i) a[i] = *(const bf16x8*)&a_lds[wr + i * 16 + l15][kof];
        #pragma unroll
        for (int j = 0; j < 2; ++j) b[j] = *(const bf16x8*)&w_lds[wc + j * 16 + l15][kof];
        #pragma unroll
        for (int i = 0; i < 4; ++i)
            #pragma unroll
            for (int j = 0; j < 2; ++j)
                acc[i][j] = __builtin_amdgcn_mfma_f32_16x16x32_bf16(a[i], b[j], acc[i][j], 0, 0, 0);
    }
    #pragma unroll
    for (int i = 0; i < 4; ++i)
        #pragma unroll
        for (int j = 0; j < 2; ++j) {
            int col_g = n0 + wc + j * 16 + l15;
            float bv = bias[col_g];
            int which = col_g >> 7, e = (col_g >> 4) & 7, d = col_g & 15;
            u16* dst = which == 0 ? Qo : (which == 1 ? Ko : Vo);
            float scl = which == 0 ? 0.25f : 1.0f;
            #pragma unroll
            for (int ii = 0; ii < 4; ++ii) {
                int row_g = m0 + wr + i * 16 + kg * 4 + ii;
                int batch = row_g % 384, sq = row_g / 384;
                dst[((size_t)(batch * 8 + e) * 192 + sq) * 16 + d] = f2bf((acc[i][j][ii] + bv) * scl);
            }
        }
}

// ---------------- fused rel-pos attention per (batch, head, w-half) -----------
// scores[w][v] = Q[w]·K[v] + Q[w]·kr[w-v+191] + K[v]·qr[w-v+191]
// fp32 score buffer sc[96][196]; cols 192 dummy, 193 rsums.
// All phases use operand order making LDS addresses affine in reg index:
//  A: (K,Q) -> row=w fixed/lane, col=v consecutive -> b128 writes
//  B: (kr,Q) -> row=w fixed/lane, col=v = vC - rr  -> imm-offset RMW
//  C: (qr,K) -> col=v fixed/lane, row=wlB + rr     -> imm-offset RMW (stride 784B)
__global__ __launch_bounds__(512, 4) void attn_kernel(const u16* __restrict__ Qg,
                                                      const u16* __restrict__ Kg,
                                                      const u16* __restrict__ Vg,
                                                      const u16* __restrict__ qr_g,
                                                      const u16* __restrict__ kr_g,
                                                      u16* __restrict__ Og) {
    __shared__ float sc[96][196];   // 75264 B
    __shared__ u16 Vt[16][200];     // 6400 B
    int tid = threadIdx.x, lane = tid & 63, wid = tid >> 6;
    int half = blockIdx.x, e = blockIdx.y, b = blockIdx.z;
    int w0 = half * 96;
    size_t base = ((size_t)b * 8 + e) * 192 * 16;

    // stage V^T (16 x 192)
    #pragma unroll
    for (int i = 0; i < 6; ++i) { int idx = tid + 512 * i;
        Vt[idx & 15][idx >> 4] = Vg[base + idx]; }

    int lo = lane & 31, hi = lane >> 5, hi8 = hi * 8;
    const u16* Qrow  = Qg + base;
    const u16* Krow  = Kg + base;
    const u16* krrow = kr_g + (size_t)e * 384 * 16;
    const u16* qrrow = qr_g + (size_t)e * 384 * 16;
    float* scf = &sc[0][0];

    // ---- Phase A: sc[w][v] = Q·K^T  (A=K, B=Q; 18 tiles) ----
    #pragma unroll
    for (int it = 0; it < 3; ++it) {
        int t = wid + 8 * it;
        if (t < 18) {
            int wt = t / 6, vt = t % 6;
            bf16x8 ak = *(const bf16x8*)(Krow + (size_t)(vt * 32 + lo) * 16 + hi8);
            bf16x8 bq = *(const bf16x8*)(Qrow + (size_t)(w0 + wt * 32 + lo) * 16 + hi8);
            f32x16 acc = {};
            acc = __builtin_amdgcn_mfma_f32_32x32x16_bf16(ak, bq, acc, 0, 0, 0);
            float* dst = &sc[wt * 32 + lo][vt * 32 + 4 * hi];
            #pragma unroll
            for (int g = 0; g < 4; ++g) {
                f32x4 vv = { acc[4 * g], acc[4 * g + 1], acc[4 * g + 2], acc[4 * g + 3] };
                *(f32x4*)(dst + 8 * g) = vv;
            }
        }
    }
    __syncthreads();

    // ---- Phase B: sc[w][v] += (Q·kr^T)[w, w+191-v]  (A=kr, B=Q; 21 tiles) ----
    #pragma unroll
    for (int it = 0; it < 3; ++it) {
        int t = wid + 8 * it;
        if (t < 21) {
            int wt, dj, partial;
            if (t < 6) { wt = t >> 1; dj = (t & 1) * 6; partial = 1; }
            else       { int u = t - 6; wt = u / 5; dj = u % 5 + 1; partial = 0; }
            int d0 = w0 + wt * 32 + dj * 32;
            bf16x8 akr = *(const bf16x8*)(krrow + (size_t)(d0 + lo) * 16 + hi8);
            bf16x8 bq  = *(const bf16x8*)(Qrow + (size_t)(w0 + wt * 32 + lo) * 16 + hi8);
            f32x16 acc = {};
            acc = __builtin_amdgcn_mfma_f32_32x32x16_bf16(akr, bq, acc, 0, 0, 0);
            int wl = wt * 32 + lo;
            int vC = lo + 191 - 32 * dj - 4 * hi;
            if (!partial) {
                float* pf = scf + wl * 196 + (vC - 27);
                #pragma unroll
                for (int ii = 0; ii < 16; ++ii) {
                    const int rr = (ii & 3) + 8 * (ii >> 2);
                    pf[27 - rr] += acc[ii];
                }
            } else {
                float* rowp = scf + wl * 196;
                #pragma unroll
                for (int ii = 0; ii < 16; ++ii) {
                    const int rr = (ii & 3) + 8 * (ii >> 2);
                    int v = vC - rr;
                    int col = ((unsigned)v < 192u) ? v : 192;
                    rowp[col] += acc[ii];
                }
            }
        }
    }
    __syncthreads();

    // ---- Phase C: sc[w][v] += K[v]·qr[w+191-v]  (A=qr, B=K; 24 tiles) ----
    #pragma unroll
    for (int it = 0; it < 3; ++it) {
        int t = wid + 8 * it;
        if (t < 24) {
            int vt, dj, partial;
            if (t < 12) { vt = t >> 1; dj = (t & 1) * 3; partial = 1; }
            else        { int u = t - 12; vt = u >> 1; dj = (u & 1) + 1; partial = 0; }
            int V0 = vt * 32;
            int d0 = w0 + 160 - V0 + dj * 32;
            bf16x8 aqr = *(const bf16x8*)(qrrow + (size_t)(d0 + lo) * 16 + hi8);
            bf16x8 bk  = *(const bf16x8*)(Krow + (size_t)(V0 + lo) * 16 + hi8);
            f32x16 acc = {};
            acc = __builtin_amdgcn_mfma_f32_32x32x16_bf16(aqr, bk, acc, 0, 0, 0);
            int wlB = 32 * dj - 31 + 4 * hi + lo;
            if (!partial) {
                float* pf = scf + wlB * 196 + V0 + lo;
                #pragma unroll
                for (int ii = 0; ii < 16; ++ii) {
                    const int rr = (ii & 3) + 8 * (ii >> 2);
                    pf[rr * 196] += acc[ii];
                }
            } else {
                #pragma unroll
                for (int ii = 0; ii < 16; ++ii) {
                    const int rr = (ii & 3) + 8 * (ii >> 2);
                    int wl = wlB + rr;
                    float* p = ((unsigned)wl < 96u) ? (scf + wl * 196 + V0 + lo)
                                                    : (scf + 192);
                    *p += acc[ii];
                }
            }
        }
    }
    __syncthreads();

    // ---- exp pass: f32 -> packed bf16 (row low half); rsum -> col 193 ----
    #pragma unroll
    for (int p = 0; p < 3; ++p) {
        int r = wid * 12 + p * 4 + (lane >> 4);
        int j = lane & 15;
        f32x4 x0 = *(const f32x4*)&sc[r][j * 12];
        f32x4 x1 = *(const f32x4*)&sc[r][j * 12 + 4];
        f32x4 x2 = *(const f32x4*)&sc[r][j * 12 + 8];
        float xs[12];
        #pragma unroll
        for (int k = 0; k < 4; ++k) { xs[k] = __expf(x0[k]); xs[4 + k] = __expf(x1[k]); xs[8 + k] = __expf(x2[k]); }
        float sum = 0.f;
        #pragma unroll
        for (int k = 0; k < 12; ++k) sum += xs[k];
        unsigned pk[6];
        #pragma unroll
        for (int k = 0; k < 6; ++k) pk[k] = cvt_pk_bf16(xs[2 * k], xs[2 * k + 1]);
        unsigned* prow32 = (unsigned*)&sc[r][0];
        *(uint2*)&prow32[j * 6]     = *(uint2*)&pk[0];
        *(uint2*)&prow32[j * 6 + 2] = *(uint2*)&pk[2];
        *(uint2*)&prow32[j * 6 + 4] = *(uint2*)&pk[4];
        sum += __shfl_xor(sum, 1);
        sum += __shfl_xor(sum, 2);
        sum += __shfl_xor(sum, 4);
        sum += __shfl_xor(sum, 8);
        if (j == 0) sc[r][193] = 1.0f / sum;
    }
    __syncthreads();

    // ---- PV: out[w][c] = sum_v P[w][v] V[v][c]  (16x16x32 over v) ----
    if (wid < 6) {
        int l15 = lane & 15, kg = lane >> 4;
        const u16* prow = (const u16*)&sc[wid * 16 + l15][0];   // packed bf16 row
        f32x4 acc = (f32x4){0.f, 0.f, 0.f, 0.f};
        #pragma unroll
        for (int kt = 0; kt < 6; ++kt) {
            bf16x8 a  = *(const bf16x8*)(prow + kt * 32 + kg * 8);
            bf16x8 bb = *(const bf16x8*)&Vt[l15][kt * 32 + kg * 8];
            acc = __builtin_amdgcn_mfma_f32_16x16x32_bf16(a, bb, acc, 0, 0, 0);
        }
        #pragma unroll
        for (int ii = 0; ii < 4; ++ii) {
            int wl = wid * 16 + kg * 4 + ii;
            float val = acc[ii] * sc[wl][193];
            Og[((size_t)(w0 + wl) * 384 + b) * 128 + e * 16 + l15] = f2bf(val);
        }
    }
}

// ---------------- output projection GEMM -------------------------------------
// MODE 0: x1[(w*384+s*192+h)] = O_row(h*384+s*192+w) @ w_out^T + b   (bf16)
// MODE 1: out[row] = O_row @ w_out^T + b + feat[row]                 (fp32)
template <int MODE>
__global__ __launch_bounds__(256) void outproj_gemm(const u16* __restrict__ X,
                                                    const float* __restrict__ Wn,
                                                    const float* __restrict__ bias,
                                                    const float* __restrict__ feat,
                                                    u16* __restrict__ x1o,
                                                    float* __restrict__ outp) {
    __shared__ u16 a_lds[128][136];
    __shared__ u16 w_lds[64][136];
    int tid = threadIdx.x;
    int m0 = blockIdx.y * 128, n0 = blockIdx.x * 64;
    #pragma unroll
    for (int i = 0; i < 8; ++i) {
        int idx = tid + 256 * i;
        int row = idx >> 4, c8 = (idx & 15) * 8;
        *(int4*)&a_lds[row][c8] = *(const int4*)&X[(size_t)(m0 + row) * 128 + c8];
    }
    #pragma unroll
    for (int i = 0; i < 8; ++i) {
        int idx = tid + 256 * i;
        int row = idx >> 5, c4 = (idx & 31) * 4;
        float4 f = *(const float4*)&Wn[(size_t)(n0 + row) * 128 + c4];
        uint2 p;
        p.x = (unsigned)f2bf(f.x) | ((unsigned)f2bf(f.y) << 16);
        p.y = (unsigned)f2bf(f.z) | ((unsigned)f2bf(f.w) << 16);
        *(uint2*)&w_lds[row][c4] = p;
    }
    __syncthreads();
    int lane = tid & 63, wid = tid >> 6;
    int wr = (wid >> 1) * 64, wc = (wid & 1) * 32;
    int kg = lane >> 4, l15 = lane & 15;
    f32x4 acc[4][2];
    #pragma unroll
    for (int i = 0; i < 4; ++i)
        #pragma unroll
        for (int j = 0; j < 2; ++j) acc[i][j] = (f32x4){0.f, 0.f, 0.f, 0.f};
    #pragma unroll
    for (int kk = 0; kk < 4; ++kk) {
        int kof = kk * 32 + kg * 8;
        bf16x8 a[4], b[2];
        #pragma unroll
        for (int i = 0; i < 4; ++i) a[i] = *(const bf16x8*)&a_lds[wr + i * 16 + l15][kof];
        #pragma unroll
        for (int j = 0; j < 2; ++j) b[j] = *(const bf16x8*)&w_lds[wc + j * 16 + l15][kof];
        #pragma unroll
        for (int i = 0; i < 4; ++i)
            #pragma unroll
            for (int j = 0; j < 2; ++j)
                acc[i][j] = __builtin_amdgcn_mfma_f32_16x16x32_bf16(a[i], b[j], acc[i][j], 0, 0, 0);
    }
    #pragma unroll
    for (int i = 0; i < 4; ++i)
        #pragma unroll
        for (int j = 0; j < 2; ++j) {
            int col_g = n0 + wc + j * 16 + l15;
            float bv = bias[col_g];
            #pragma unroll
            for (int ii = 0; ii < 4; ++ii) {
                int row_g = m0 + wr + i * 16 + kg * 4 + ii;
                float val = acc[i][j][ii] + bv;
                if (MODE == 0) {
                    int h = row_g / 384, rem = row_g % 384, s2 = rem / 192, w = rem % 192;
                    x1o[((size_t)(w * 384 + s2 * 192 + h)) * 128 + col_g] = f2bf(val);
                } else {
                    size_t o = (size_t)row_g * 128 + col_g;
                    outp[o] = val + feat[o];
                }
            }
        }
}

extern "C" void kernel_launch(void* const* d_in, const int* in_sizes, int n_in,
                              void* d_out, int out_size, void* d_ws, size_t ws_size,
                              hipStream_t stream) {
    const float* feat   = (const float*)d_in[0];
    const float* pos    = (const float*)d_in[1];
    const float* pos_y  = (const float*)d_in[2];
    const float* ln_w   = (const float*)d_in[3];
    const float* ln_b   = (const float*)d_in[4];
    const float* w_in1  = (const float*)d_in[5];
    const float* b_in1  = (const float*)d_in[6];
    const float* w_out1 = (const float*)d_in[7];
    const float* b_out1 = (const float*)d_in[8];
    const float* w_in2  = (const float*)d_in[9];
    const float* b_in2  = (const float*)d_in[10];
    const float* w_out2 = (const float*)d_in[11];
    const float* b_out2 = (const float*)d_in[12];
    float* out = (float*)d_out;

    char* ws = (char*)d_ws;
    const size_t R = (size_t)73728 * 128;   // 9,437,184 elements
    u16* x2 = (u16*)ws; ws += R * 2;
    u16* x1 = (u16*)ws; ws += R * 2;
    u16* Q  = (u16*)ws; ws += R * 2;
    u16* K  = (u16*)ws; ws += R * 2;
    u16* V  = (u16*)ws; ws += R * 2;
    u16* O  = (u16*)ws; ws += R * 2;
    u16* qr = (u16*)ws; ws += (size_t)8 * 384 * 16 * 2;
    u16* kr = (u16*)ws; ws += (size_t)8 * 384 * 16 * 2;

    // ---- layer 2 (vertical axis) ----
    ln_kernel<<<18432, 256, 0, stream>>>(feat, ln_w, ln_b, x2);
    posproj_kernel<<<384, 256, 0, stream>>>(pos_y, w_in2, b_in2, qr, kr);
    qkv_gemm<<<dim3(6, 576), 256, 0, stream>>>(x2, w_in2, b_in2, Q, K, V);
    attn_kernel<<<dim3(2, 8, 384), 512, 0, stream>>>(Q, K, V, qr, kr, O);
    outproj_gemm<0><<<dim3(2, 576), 256, 0, stream>>>(O, w_out2, b_out2, nullptr, x1, nullptr);
    // ---- layer 1 (horizontal axis) ----
    posproj_kernel<<<384, 256, 0, stream>>>(pos, w_in1, b_in1, qr, kr);
    qkv_gemm<<<dim3(6, 576), 256, 0, stream>>>(x1, w_in1, b_in1, Q, K, V);
    attn_kernel<<<dim3(2, 8, 384), 512, 0, stream>>>(Q, K, V, qr, kr, O);
    outproj_gemm<1><<<dim3(2, 576), 256, 0, stream>>>(O, w_out1, b_out1, feat, nullptr, out);
}